// Round 6
// baseline (567.750 us; speedup 1.0000x reference)
//
#include <hip/hip_runtime.h>
#include <math.h>

#define BB 512
#define TT 512
#define OO 64

// =====================================================================
// Kernel 1: transpose trans (16 KB) into ws so conf-pass rows coalesce
// Tt[g*64+i] = trans[i*64+g] = T[i][g]
// =====================================================================
__global__ void crf_transpose(const float* __restrict__ trans,
                              float* __restrict__ Tt) {
    for (int k = threadIdx.x; k < OO * OO; k += 256)
        Tt[k] = trans[(k & 63) * OO + (k >> 6)];
}

// =====================================================================
// Kernel 2: single-wave Viterbi scan. Broadcast via ds_bpermute
// ROTATIONS: all 63 rotations depend only on s -> fully pipelined DS
// ops, no SGPR hazards, no serialized lgkmcnt chains.
//   M[j] = max_r ( s[(j+r)&63] + Trot[r] ),  Trot[r] = T[(j+r)&63][j]
// Streams M_t to ws; backpointers recovered exactly by ballot-backtrack
// (fmax is exact selection => recomputed candidate == M bit-exact).
// =====================================================================
__global__ __launch_bounds__(64) void crf_scan(
    const float* __restrict__ logits,   // [B][T][O]
    const float* __restrict__ trans,    // [O][O]
    const int*   __restrict__ seqlens,  // [B]
    float* __restrict__ out_tags,       // [B][T] (f32)
    float* __restrict__ Mst)            // ws: [B][T][O] f32  (M_0 = 0 row)
{
    const int b = blockIdx.x;
    const int j = threadIdx.x;          // tag 0..63 (also "i" in backtrack)

    __shared__ float Tt_lds[OO * OO];   // Tt_lds[g*64+i] = T[i][g]
    __shared__ unsigned char tagl[TT];

    const int L = seqlens[b];
    const float* lg = logits + (size_t)b * TT * OO;
    float* Mw = Mst + (size_t)b * TT * OO;

    // ---- load T row j per lane (16 x float4), build Tt_lds CONFLICT-FREE:
    // lane j writes Tt_lds[g*64 + j] = T[j][g]  (consecutive lanes ->
    // consecutive banks). Also gather Trot[r] = T[(j+r)&63][j].
    {
        const float4* rowp = (const float4*)(trans + j * OO);
        #pragma unroll
        for (int q = 0; q < 16; ++q) {
            float4 rv = rowp[q];
            Tt_lds[(4*q+0) * OO + j] = rv.x;
            Tt_lds[(4*q+1) * OO + j] = rv.y;
            Tt_lds[(4*q+2) * OO + j] = rv.z;
            Tt_lds[(4*q+3) * OO + j] = rv.w;
        }
    }
    float Trot[64];
    #pragma unroll
    for (int r = 0; r < 64; ++r)
        Trot[r] = trans[((j + r) & 63) * OO + j];

    float s = lg[j];                    // state in register, one per lane
    Mw[j] = 0.f;                        // M_0 := 0  (s_0 = x_0 + M_0)

    // 4-deep emission prefetch
    float xr1 = (L > 1) ? lg[1 * OO + j] : 0.f;
    float xr2 = (L > 2) ? lg[2 * OO + j] : 0.f;
    float xr3 = (L > 3) ? lg[3 * OO + j] : 0.f;
    float xr4 = (L > 4) ? lg[4 * OO + j] : 0.f;

    const int la4 = j << 2;             // byte index for bpermute

    for (int t = 1; t < L; ++t) {
        float x = xr1;
        xr1 = xr2; xr2 = xr3; xr3 = xr4;
        if (t + 4 < L) xr4 = lg[(t + 4) * OO + j];

        const int su = __float_as_int(s);
        float m = s + Trot[0];          // r = 0: identity rotation
        // groups of 8 rotations; every bpermute depends only on s
        #pragma unroll
        for (int g = 0; g < 8; ++g) {
            float c0, c1, c2, c3, c4, c5, c6, c7;
            int base = 8 * g;
            if (g == 0) {
                // r = 1..7
                c1 = __int_as_float(__builtin_amdgcn_ds_bpermute(la4 + 4*1, su)) + Trot[1];
                c2 = __int_as_float(__builtin_amdgcn_ds_bpermute(la4 + 4*2, su)) + Trot[2];
                c3 = __int_as_float(__builtin_amdgcn_ds_bpermute(la4 + 4*3, su)) + Trot[3];
                c4 = __int_as_float(__builtin_amdgcn_ds_bpermute(la4 + 4*4, su)) + Trot[4];
                c5 = __int_as_float(__builtin_amdgcn_ds_bpermute(la4 + 4*5, su)) + Trot[5];
                c6 = __int_as_float(__builtin_amdgcn_ds_bpermute(la4 + 4*6, su)) + Trot[6];
                c7 = __int_as_float(__builtin_amdgcn_ds_bpermute(la4 + 4*7, su)) + Trot[7];
                float t12 = fmaxf(c1, c2), t34 = fmaxf(c3, c4);
                float t56 = fmaxf(c5, c6);
                m = fmaxf(m, fmaxf(fmaxf(t12, t34), fmaxf(t56, c7)));
            } else {
                c0 = __int_as_float(__builtin_amdgcn_ds_bpermute(la4 + 4*(base+0), su)) + Trot[base+0];
                c1 = __int_as_float(__builtin_amdgcn_ds_bpermute(la4 + 4*(base+1), su)) + Trot[base+1];
                c2 = __int_as_float(__builtin_amdgcn_ds_bpermute(la4 + 4*(base+2), su)) + Trot[base+2];
                c3 = __int_as_float(__builtin_amdgcn_ds_bpermute(la4 + 4*(base+3), su)) + Trot[base+3];
                c4 = __int_as_float(__builtin_amdgcn_ds_bpermute(la4 + 4*(base+4), su)) + Trot[base+4];
                c5 = __int_as_float(__builtin_amdgcn_ds_bpermute(la4 + 4*(base+5), su)) + Trot[base+5];
                c6 = __int_as_float(__builtin_amdgcn_ds_bpermute(la4 + 4*(base+6), su)) + Trot[base+6];
                c7 = __int_as_float(__builtin_amdgcn_ds_bpermute(la4 + 4*(base+7), su)) + Trot[base+7];
                float t01 = fmaxf(c0, c1), t23 = fmaxf(c2, c3);
                float t45 = fmaxf(c4, c5), t67 = fmaxf(c6, c7);
                m = fmaxf(m, fmaxf(fmaxf(t01, t23), fmaxf(t45, t67)));
            }
        }

        Mw[t * OO + j] = m;             // stream the pre-emission max
        s = x + m;                      // loop-carried: pure registers
    }

    // ---- final argmax over lanes (first-max, exact) ----
    float mm = s;
    #pragma unroll
    for (int d = 1; d < 64; d <<= 1)
        mm = fmaxf(mm, __shfl_xor(mm, d));
    unsigned long long bal = __ballot(s == mm);
    int gcur = (int)__builtin_ctzll(bal);

    // ---- fused exact backtrack: first i with d_i == M_t[gcur] ----
    int t = L - 1;
    if (j == 0) tagl[t] = (unsigned char)gcur;

    float Mt = Mw[t * OO + j];                          // M_t row (per-lane)
    float Xp = (t >= 1) ? lg[(t - 1) * OO + j] : 0.f;   // x_{t-1} row
    float Mp = (t >= 1) ? Mw[(t - 1) * OO + j] : 0.f;   // M_{t-1} row
    float Xq = (t >= 2) ? lg[(t - 2) * OO + j] : 0.f;   // prefetch t-2
    float Mq = (t >= 2) ? Mw[(t - 2) * OO + j] : 0.f;

    while (t >= 1) {
        float target = __uint_as_float(
            (unsigned)__builtin_amdgcn_readlane(__float_as_uint(Mt), gcur));
        float d = (Xp + Mp) + Tt_lds[gcur * OO + j];    // bit-exact recompute
        unsigned long long bl = __ballot(d == target);
        gcur = (int)__builtin_ctzll(bl);                // first-max semantics
        if (j == 0) tagl[t - 1] = (unsigned char)gcur;
        Mt = Mp; Xp = Xq; Mp = Mq;
        if (t >= 3) {
            Xq = lg[(t - 3) * OO + j];
            Mq = Mw[(t - 3) * OO + j];
        }
        --t;
    }
    asm volatile("" ::: "memory");      // lane0 tagl writes before wave reads

    float* ot = out_tags + (size_t)b * TT;
    for (int p = j; p < TT; p += 64)
        ot[p] = (p < L) ? (float)tagl[p] : 0.f;
}

// =====================================================================
// Kernel 3: confidences for decoded path only. One wave per (b,p).
// s_p = x_p + M_p (bit-exact reconstruction);
// conf = 1 / sum_i exp(v_i - max v),  v_i = s_p[i] + T[i][tag_{p+1}]
// (v_i = s_p[i] for p == L-1). Exact f32.
// =====================================================================
__global__ __launch_bounds__(256) void crf_conf(
    const float* __restrict__ logits,   // [B][T][O]
    const float* __restrict__ Mst,      // ws: [B][T][O]
    const float* __restrict__ Tt,       // ws: [O][O] transposed
    const float* __restrict__ out_tags, // [B][T]
    const int*   __restrict__ seqlens,  // [B]
    float* __restrict__ out_scores)     // [B][T]
{
    const int b = blockIdx.x >> 7;
    const int p = ((blockIdx.x & 127) << 2) + (threadIdx.x >> 6);
    const int i = threadIdx.x & 63;
    const int L = seqlens[b];

    if (p >= L) {
        if (i == 0) out_scores[(size_t)b * TT + p] = 0.f;
        return;
    }

    const size_t row = ((size_t)b * TT + p) * OO;
    float v = logits[row + i] + Mst[row + i];
    if (p < L - 1) {
        int g = (int)out_tags[(size_t)b * TT + p + 1];
        v += Tt[g * OO + i];
    }

    float m = v;
    #pragma unroll
    for (int d = 1; d < 64; d <<= 1)
        m = fmaxf(m, __shfl_xor(m, d));
    float e = __expf(v - m);
    #pragma unroll
    for (int d = 1; d < 64; d <<= 1)
        e += __shfl_xor(e, d);

    if (i == 0)
        out_scores[(size_t)b * TT + p] = 1.0f / e;
}

// =====================================================================
// Fallback (proven round-1 kernel): used only if ws too small
// =====================================================================
__global__ __launch_bounds__(256) void crf_decode_fallback(
    const float* __restrict__ logits,
    const float* __restrict__ trans,
    const int*   __restrict__ seqlens,
    float* __restrict__ out)
{
    const int b   = blockIdx.x;
    const int tid = threadIdx.x;
    const int j   = tid >> 2;
    const int c   = tid & 3;

    __shared__ unsigned char bpl[TT][OO];
    __shared__ unsigned char scl[TT][OO];
    __shared__ float st[2][OO];

    const int L = seqlens[b];
    const float* lg = logits + (size_t)b * TT * OO;

    float trc[16];
    #pragma unroll
    for (int i2 = 0; i2 < 16; ++i2)
        trc[i2] = trans[(c * 16 + i2) * OO + j];

    if (tid < OO) st[0][tid] = lg[tid];
    __syncthreads();

    int cur = 0;
    for (int t = 1; t < L; ++t) {
        float x = lg[t * OO + j];
        float v[16];
        float m = -1e30f;
        int   idx = 0;
        #pragma unroll
        for (int i2 = 0; i2 < 16; ++i2) {
            float val = st[cur][c * 16 + i2] + trc[i2];
            v[i2] = val;
            if (val > m) { m = val; idx = c * 16 + i2; }
        }
        #pragma unroll
        for (int d = 1; d <= 2; d <<= 1) {
            float mo = __shfl_xor(m, d);
            int   io = __shfl_xor(idx, d);
            if (mo > m || (mo == m && io < idx)) { m = mo; idx = io; }
        }
        float sden = 0.f;
        #pragma unroll
        for (int i2 = 0; i2 < 16; ++i2)
            sden += __expf(v[i2] - m);
        #pragma unroll
        for (int d = 1; d <= 2; d <<= 1)
            sden += __shfl_xor(sden, d);

        if (c == 0) {
            st[cur ^ 1][j] = x + m;
            bpl[t][j] = (unsigned char)idx;
            float conf = fminf(1.0f / sden, 1.0f);
            scl[t][j] = (unsigned char)(conf * 255.0f + 0.5f);
        }
        cur ^= 1;
        __syncthreads();
    }

    if (tid == 0) {
        float m = -1e30f; int idx = 0;
        for (int jj = 0; jj < OO; ++jj) {
            float vv = st[cur][jj];
            if (vv > m) { m = vv; idx = jj; }
        }
        float sden = 0.f;
        for (int jj = 0; jj < OO; ++jj)
            sden += __expf(st[cur][jj] - m);

        float* out_tags   = out + (size_t)b * TT;
        float* out_scores = out + (size_t)BB * TT + (size_t)b * TT;
        out_tags[L - 1]   = (float)idx;
        out_scores[L - 1] = 1.0f / sden;

        int tag = idx;
        for (int t = L - 1; t >= 1; --t) {
            int ntag  = bpl[t][tag];
            float sc  = (float)scl[t][tag] * (1.0f / 255.0f);
            out_tags[t - 1]   = (float)ntag;
            out_scores[t - 1] = sc;
            tag = ntag;
        }
    }

    float* out_tags   = out + (size_t)b * TT;
    float* out_scores = out + (size_t)BB * TT + (size_t)b * TT;
    for (int p = L + tid; p < TT; p += 256) {
        out_tags[p]   = 0.f;
        out_scores[p] = 0.f;
    }
}

extern "C" void kernel_launch(void* const* d_in, const int* in_sizes, int n_in,
                              void* d_out, int out_size, void* d_ws, size_t ws_size,
                              hipStream_t stream) {
    const float* logits = (const float*)d_in[0];
    const float* trans  = (const float*)d_in[1];
    const int*   lens   = (const int*)d_in[2];
    float* out = (float*)d_out;

    const size_t m_bytes  = (size_t)BB * TT * OO * sizeof(float); // 64 MB
    const size_t tt_bytes = (size_t)OO * OO * sizeof(float);      // 16 KB
    if (ws_size >= m_bytes + tt_bytes) {
        float* Mst = (float*)d_ws;
        float* Tt  = (float*)((char*)d_ws + m_bytes);
        float* out_tags   = out;
        float* out_scores = out + (size_t)BB * TT;

        crf_transpose<<<1, 256, 0, stream>>>(trans, Tt);
        crf_scan<<<BB, 64, 0, stream>>>(logits, trans, lens, out_tags, Mst);
        crf_conf<<<BB * 128, 256, 0, stream>>>(logits, Mst, Tt, out_tags, lens,
                                               out_scores);
    } else {
        crf_decode_fallback<<<BB, 256, 0, stream>>>(logits, trans, lens, out);
    }
}

// Round 7
// 386.365 us; speedup vs baseline: 1.4695x; 1.4695x over previous
//
#include <hip/hip_runtime.h>
#include <math.h>

#define BB 512
#define TT 512
#define OO 64

typedef float f32x4 __attribute__((ext_vector_type(4)));

// =====================================================================
// Kernel 1: transpose trans (16 KB) into ws so conf-pass rows coalesce
// Tt[g*64+i] = trans[i*64+g] = T[i][g]
// =====================================================================
__global__ void crf_transpose(const float* __restrict__ trans,
                              float* __restrict__ Tt) {
    for (int k = threadIdx.x; k < OO * OO; k += 256)
        Tt[k] = trans[(k & 63) * OO + (k >> 6)];
}

// =====================================================================
// Kernel 2: single-wave Viterbi scan; broadcast = ONE asm block:
// ds_write_b32(new s) + 16x ds_read_b128 (uniform addr = broadcast,
// conflict-free) + single s_waitcnt lgkmcnt(0). One latency hop/step
// instead of the compiler's 16 serialized read->wait->use chains (R3)
// or 64 readlane SGPR hazards (R4/R5) or grouped bpermute waits (R6).
// Same-wave DS ops execute in order => write-then-read is race-free.
// Streams M_t to ws; backpointers recovered exactly by ballot-backtrack.
// =====================================================================
__global__ __launch_bounds__(64) void crf_scan(
    const float* __restrict__ logits,   // [B][T][O]
    const float* __restrict__ trans,    // [O][O]
    const int*   __restrict__ seqlens,  // [B]
    float* __restrict__ out_tags,       // [B][T] (f32)
    float* __restrict__ Mst)            // ws: [B][T][O] f32  (M_0 = 0 row)
{
    const int b = blockIdx.x;
    const int j = threadIdx.x;          // tag 0..63 (also "i" in backtrack)

    __shared__ __align__(16) float st[OO];
    __shared__ float Tt_lds[OO * OO];   // Tt_lds[g*64+i] = T[i][g]
    __shared__ unsigned char tagl[TT];

    const int L = seqlens[b];
    const float* lg = logits + (size_t)b * TT * OO;
    float* Mw = Mst + (size_t)b * TT * OO;

    // build Tt_lds conflict-free (lane j writes column j of each row)
    {
        const f32x4* rowp = (const f32x4*)(trans + j * OO);
        #pragma unroll
        for (int q = 0; q < 16; ++q) {
            f32x4 rv = rowp[q];
            Tt_lds[(4*q+0) * OO + j] = rv[0];
            Tt_lds[(4*q+1) * OO + j] = rv[1];
            Tt_lds[(4*q+2) * OO + j] = rv[2];
            Tt_lds[(4*q+3) * OO + j] = rv[3];
        }
    }
    // lane j: transition column T[i][j] in registers (coalesced loads)
    float Tc[64];
    #pragma unroll
    for (int r = 0; r < 64; ++r)
        Tc[r] = trans[r * OO + j];

    // LDS byte addresses for asm (gfx9+: shared aperture is 4GB-aligned,
    // so low 32 bits of a flat shared address == LDS byte offset)
    const unsigned stbase = (unsigned)(size_t)&st[0];
    const unsigned wrAddr = stbase + (unsigned)(j * 4);

    float s = lg[j];                    // state: one value per lane
    Mw[j] = 0.f;                        // M_0 := 0  (s_0 = x_0 + M_0)
    asm volatile("ds_write_b32 %0, %1" :: "v"(wrAddr), "v"(s));

    // 4-deep emission prefetch
    float xr1 = (L > 1) ? lg[1 * OO + j] : 0.f;
    float xr2 = (L > 2) ? lg[2 * OO + j] : 0.f;
    float xr3 = (L > 3) ? lg[3 * OO + j] : 0.f;
    float xr4 = (L > 4) ? lg[4 * OO + j] : 0.f;

    const float* lgp = lg + 5 * OO + j;   // -> x_{t+4} at t=1
    float*       mwp = Mw + OO + j;       // -> M_1 slot

    for (int t = 1; t < L; ++t) {
        float x = xr1; xr1 = xr2; xr2 = xr3; xr3 = xr4;
        if (t + 4 < L) xr4 = *lgp;
        lgp += OO;

        f32x4 r0,r1,r2,r3,r4,r5,r6,r7,r8,r9,r10,r11,r12,r13,r14,r15;
        asm volatile(
            "ds_read_b128 %0, %16 offset:0\n\t"
            "ds_read_b128 %1, %16 offset:16\n\t"
            "ds_read_b128 %2, %16 offset:32\n\t"
            "ds_read_b128 %3, %16 offset:48\n\t"
            "ds_read_b128 %4, %16 offset:64\n\t"
            "ds_read_b128 %5, %16 offset:80\n\t"
            "ds_read_b128 %6, %16 offset:96\n\t"
            "ds_read_b128 %7, %16 offset:112\n\t"
            "ds_read_b128 %8, %16 offset:128\n\t"
            "ds_read_b128 %9, %16 offset:144\n\t"
            "ds_read_b128 %10, %16 offset:160\n\t"
            "ds_read_b128 %11, %16 offset:176\n\t"
            "ds_read_b128 %12, %16 offset:192\n\t"
            "ds_read_b128 %13, %16 offset:208\n\t"
            "ds_read_b128 %14, %16 offset:224\n\t"
            "ds_read_b128 %15, %16 offset:240\n\t"
            "s_waitcnt lgkmcnt(0)"
            : "=v"(r0), "=v"(r1), "=v"(r2), "=v"(r3),
              "=v"(r4), "=v"(r5), "=v"(r6), "=v"(r7),
              "=v"(r8), "=v"(r9), "=v"(r10), "=v"(r11),
              "=v"(r12), "=v"(r13), "=v"(r14), "=v"(r15)
            : "v"(stbase));
        __builtin_amdgcn_sched_barrier(0);   // rule-18: pin VALU after wait

        // candidates + max tree (max3-friendly), 4 independent partials
        float m0, m1, m2, m3;
        #define QUAD(q, rr, acc, first)                                   \
        {                                                                 \
            float c0 = rr[0] + Tc[4*(q)+0];                               \
            float c1 = rr[1] + Tc[4*(q)+1];                               \
            float c2 = rr[2] + Tc[4*(q)+2];                               \
            float c3 = rr[3] + Tc[4*(q)+3];                               \
            float mq = fmaxf(fmaxf(fmaxf(c0, c1), c2), c3);               \
            acc = first ? mq : fmaxf(acc, mq);                            \
        }
        QUAD(0,  r0,  m0, 1) QUAD(1,  r1,  m1, 1)
        QUAD(2,  r2,  m2, 1) QUAD(3,  r3,  m3, 1)
        QUAD(4,  r4,  m0, 0) QUAD(5,  r5,  m1, 0)
        QUAD(6,  r6,  m2, 0) QUAD(7,  r7,  m3, 0)
        QUAD(8,  r8,  m0, 0) QUAD(9,  r9,  m1, 0)
        QUAD(10, r10, m2, 0) QUAD(11, r11, m3, 0)
        QUAD(12, r12, m0, 0) QUAD(13, r13, m1, 0)
        QUAD(14, r14, m2, 0) QUAD(15, r15, m3, 0)
        #undef QUAD
        float m = fmaxf(fmaxf(m0, m1), fmaxf(m2, m3));

        *mwp = m; mwp += OO;            // stream pre-emission max (off-path)
        s = x + m;
        asm volatile("ds_write_b32 %0, %1" :: "v"(wrAddr), "v"(s));
    }

    // ---- final argmax over lanes (first-max, exact) ----
    float mm = s;
    #pragma unroll
    for (int d = 1; d < 64; d <<= 1)
        mm = fmaxf(mm, __shfl_xor(mm, d));
    unsigned long long bal = __ballot(s == mm);
    int gcur = (int)__builtin_ctzll(bal);

    // ---- fused exact backtrack: first i with d_i == M_t[gcur] ----
    int t = L - 1;
    if (j == 0) tagl[t] = (unsigned char)gcur;

    float Mt = Mw[t * OO + j];                          // M_t row (per-lane)
    float Xp = (t >= 1) ? lg[(t - 1) * OO + j] : 0.f;   // x_{t-1} row
    float Mp = (t >= 1) ? Mw[(t - 1) * OO + j] : 0.f;   // M_{t-1} row
    float Xq = (t >= 2) ? lg[(t - 2) * OO + j] : 0.f;   // prefetch t-2
    float Mq = (t >= 2) ? Mw[(t - 2) * OO + j] : 0.f;

    while (t >= 1) {
        float target = __uint_as_float(
            (unsigned)__builtin_amdgcn_readlane(__float_as_uint(Mt), gcur));
        float d = (Xp + Mp) + Tt_lds[gcur * OO + j];    // bit-exact recompute
        unsigned long long bl = __ballot(d == target);
        gcur = (int)__builtin_ctzll(bl);                // first-max semantics
        if (j == 0) tagl[t - 1] = (unsigned char)gcur;
        Mt = Mp; Xp = Xq; Mp = Mq;
        if (t >= 3) {
            Xq = lg[(t - 3) * OO + j];
            Mq = Mw[(t - 3) * OO + j];
        }
        --t;
    }
    asm volatile("" ::: "memory");      // lane0 tagl writes before wave reads

    float* ot = out_tags + (size_t)b * TT;
    for (int p = j; p < TT; p += 64)
        ot[p] = (p < L) ? (float)tagl[p] : 0.f;
}

// =====================================================================
// Kernel 3: confidences for decoded path only. One wave per (b,p).
// s_p = x_p + M_p (bit-exact reconstruction);
// conf = 1 / sum_i exp(v_i - max v),  v_i = s_p[i] + T[i][tag_{p+1}]
// (v_i = s_p[i] for p == L-1). Exact f32.
// =====================================================================
__global__ __launch_bounds__(256) void crf_conf(
    const float* __restrict__ logits,   // [B][T][O]
    const float* __restrict__ Mst,      // ws: [B][T][O]
    const float* __restrict__ Tt,       // ws: [O][O] transposed
    const float* __restrict__ out_tags, // [B][T]
    const int*   __restrict__ seqlens,  // [B]
    float* __restrict__ out_scores)     // [B][T]
{
    const int b = blockIdx.x >> 7;
    const int p = ((blockIdx.x & 127) << 2) + (threadIdx.x >> 6);
    const int i = threadIdx.x & 63;
    const int L = seqlens[b];

    if (p >= L) {
        if (i == 0) out_scores[(size_t)b * TT + p] = 0.f;
        return;
    }

    const size_t row = ((size_t)b * TT + p) * OO;
    float v = logits[row + i] + Mst[row + i];
    if (p < L - 1) {
        int g = (int)out_tags[(size_t)b * TT + p + 1];
        v += Tt[g * OO + i];
    }

    float m = v;
    #pragma unroll
    for (int d = 1; d < 64; d <<= 1)
        m = fmaxf(m, __shfl_xor(m, d));
    float e = __expf(v - m);
    #pragma unroll
    for (int d = 1; d < 64; d <<= 1)
        e += __shfl_xor(e, d);

    if (i == 0)
        out_scores[(size_t)b * TT + p] = 1.0f / e;
}

// =====================================================================
// Fallback (proven round-1 kernel): used only if ws too small
// =====================================================================
__global__ __launch_bounds__(256) void crf_decode_fallback(
    const float* __restrict__ logits,
    const float* __restrict__ trans,
    const int*   __restrict__ seqlens,
    float* __restrict__ out)
{
    const int b   = blockIdx.x;
    const int tid = threadIdx.x;
    const int j   = tid >> 2;
    const int c   = tid & 3;

    __shared__ unsigned char bpl[TT][OO];
    __shared__ unsigned char scl[TT][OO];
    __shared__ float st[2][OO];

    const int L = seqlens[b];
    const float* lg = logits + (size_t)b * TT * OO;

    float trc[16];
    #pragma unroll
    for (int i2 = 0; i2 < 16; ++i2)
        trc[i2] = trans[(c * 16 + i2) * OO + j];

    if (tid < OO) st[0][tid] = lg[tid];
    __syncthreads();

    int cur = 0;
    for (int t = 1; t < L; ++t) {
        float x = lg[t * OO + j];
        float v[16];
        float m = -1e30f;
        int   idx = 0;
        #pragma unroll
        for (int i2 = 0; i2 < 16; ++i2) {
            float val = st[cur][c * 16 + i2] + trc[i2];
            v[i2] = val;
            if (val > m) { m = val; idx = c * 16 + i2; }
        }
        #pragma unroll
        for (int d = 1; d <= 2; d <<= 1) {
            float mo = __shfl_xor(m, d);
            int   io = __shfl_xor(idx, d);
            if (mo > m || (mo == m && io < idx)) { m = mo; idx = io; }
        }
        float sden = 0.f;
        #pragma unroll
        for (int i2 = 0; i2 < 16; ++i2)
            sden += __expf(v[i2] - m);
        #pragma unroll
        for (int d = 1; d <= 2; d <<= 1)
            sden += __shfl_xor(sden, d);

        if (c == 0) {
            st[cur ^ 1][j] = x + m;
            bpl[t][j] = (unsigned char)idx;
            float conf = fminf(1.0f / sden, 1.0f);
            scl[t][j] = (unsigned char)(conf * 255.0f + 0.5f);
        }
        cur ^= 1;
        __syncthreads();
    }

    if (tid == 0) {
        float m = -1e30f; int idx = 0;
        for (int jj = 0; jj < OO; ++jj) {
            float vv = st[cur][jj];
            if (vv > m) { m = vv; idx = jj; }
        }
        float sden = 0.f;
        for (int jj = 0; jj < OO; ++jj)
            sden += __expf(st[cur][jj] - m);

        float* out_tags   = out + (size_t)b * TT;
        float* out_scores = out + (size_t)BB * TT + (size_t)b * TT;
        out_tags[L - 1]   = (float)idx;
        out_scores[L - 1] = 1.0f / sden;

        int tag = idx;
        for (int t = L - 1; t >= 1; --t) {
            int ntag  = bpl[t][tag];
            float sc  = (float)scl[t][tag] * (1.0f / 255.0f);
            out_tags[t - 1]   = (float)ntag;
            out_scores[t - 1] = sc;
            tag = ntag;
        }
    }

    float* out_tags   = out + (size_t)b * TT;
    float* out_scores = out + (size_t)BB * TT + (size_t)b * TT;
    for (int p = L + tid; p < TT; p += 256) {
        out_tags[p]   = 0.f;
        out_scores[p] = 0.f;
    }
}

extern "C" void kernel_launch(void* const* d_in, const int* in_sizes, int n_in,
                              void* d_out, int out_size, void* d_ws, size_t ws_size,
                              hipStream_t stream) {
    const float* logits = (const float*)d_in[0];
    const float* trans  = (const float*)d_in[1];
    const int*   lens   = (const int*)d_in[2];
    float* out = (float*)d_out;

    const size_t m_bytes  = (size_t)BB * TT * OO * sizeof(float); // 64 MB
    const size_t tt_bytes = (size_t)OO * OO * sizeof(float);      // 16 KB
    if (ws_size >= m_bytes + tt_bytes) {
        float* Mst = (float*)d_ws;
        float* Tt  = (float*)((char*)d_ws + m_bytes);
        float* out_tags   = out;
        float* out_scores = out + (size_t)BB * TT;

        crf_transpose<<<1, 256, 0, stream>>>(trans, Tt);
        crf_scan<<<BB, 64, 0, stream>>>(logits, trans, lens, out_tags, Mst);
        crf_conf<<<BB * 128, 256, 0, stream>>>(logits, Mst, Tt, out_tags, lens,
                                               out_scores);
    } else {
        crf_decode_fallback<<<BB, 256, 0, stream>>>(logits, trans, lens, out);
    }
}

// Round 10
// 377.209 us; speedup vs baseline: 1.5051x; 1.0243x over previous
//
#include <hip/hip_runtime.h>
#include <math.h>

#define BB 512
#define TT 512
#define OO 64

typedef float f32x4 __attribute__((ext_vector_type(4)));

// =====================================================================
// Kernel 1: transpose trans (16 KB) into ws so conf-pass rows coalesce
// Tt[g*64+i] = trans[i*64+g] = T[i][g]
// =====================================================================
__global__ void crf_transpose(const float* __restrict__ trans,
                              float* __restrict__ Tt) {
    for (int k = threadIdx.x; k < OO * OO; k += 256)
        Tt[k] = trans[(k & 63) * OO + (k >> 6)];
}

// =====================================================================
// Kernel 2: single-wave Viterbi scan (R7-passing structure).
// State broadcast = ONE asm batch: ds_write_b32(s) at loop end, then at
// loop top 16x ds_read_b128 from the wave-uniform state base + single
// s_waitcnt lgkmcnt(0) (one latency hop/step). Same-wave DS ops are
// processed in order => write-then-read is race-free without barriers.
// launch_bounds(64,1): we are grid-capped at 2 blocks/CU anyway, so let
// the allocator keep Tc[64] + 64 asm-output VGPRs resident. R7's
// VGPR_Count=72 proved Tc was spilled to scratch and reloaded in-loop
// (FETCH 16.7->40MB when Tc[64] appeared) -- the hidden ~1000 cyc/step.
// Streams M_t to ws; backpointers recovered exactly by ballot-backtrack
// (fmax is an exact selection => recomputed candidate == M bit-exact).
// =====================================================================
__global__ __launch_bounds__(64, 1) void crf_scan(
    const float* __restrict__ logits,   // [B][T][O]
    const float* __restrict__ trans,    // [O][O]
    const int*   __restrict__ seqlens,  // [B]
    float* __restrict__ out_tags,       // [B][T] (f32)
    float* __restrict__ Mst)            // ws: [B][T][O] f32  (M_0 = 0 row)
{
    const int b = blockIdx.x;
    const int j = threadIdx.x;          // tag 0..63 (also "i" in backtrack)

    __shared__ __align__(16) float st[OO];
    __shared__ float Tt_lds[OO * OO];   // Tt_lds[g*64+i] = T[i][g]
    __shared__ unsigned char tagl[TT];

    const int L = seqlens[b];
    const float* lg = logits + (size_t)b * TT * OO;
    float* Mw = Mst + (size_t)b * TT * OO;

    // build Tt_lds conflict-free (lane j writes column j of each row)
    {
        const f32x4* rowp = (const f32x4*)(trans + j * OO);
        #pragma unroll
        for (int q = 0; q < 16; ++q) {
            f32x4 rv = rowp[q];
            Tt_lds[(4*q+0) * OO + j] = rv[0];
            Tt_lds[(4*q+1) * OO + j] = rv[1];
            Tt_lds[(4*q+2) * OO + j] = rv[2];
            Tt_lds[(4*q+3) * OO + j] = rv[3];
        }
    }
    // lane j: transition column T[i][j] in registers (coalesced loads)
    float Tc[64];
    #pragma unroll
    for (int r = 0; r < 64; ++r)
        Tc[r] = trans[r * OO + j];

    // LDS byte addresses for asm (gfx9+: shared aperture 4GB-aligned, so
    // low 32 bits of a flat shared address == LDS byte offset)
    const unsigned stbase = (unsigned)(size_t)&st[0];
    const unsigned wrAddr = stbase + (unsigned)(j * 4);

    float s = lg[j];                    // state: one value per lane
    Mw[j] = 0.f;                        // M_0 := 0  (s_0 = x_0 + M_0)
    asm volatile("ds_write_b32 %0, %1" :: "v"(wrAddr), "v"(s));

    // 4-deep emission prefetch, branchless (rows 1..4 always exist;
    // values past L are loaded but never consumed: loop runs t < L)
    float xr1 = lg[1 * OO + j];
    float xr2 = lg[2 * OO + j];
    float xr3 = lg[3 * OO + j];
    float xr4 = lg[4 * OO + j];

    const float* lgp = lg + 5 * OO + j;   // -> x_{t+4} at t=1 (post-load adv)
    float*       mwp = Mw + OO + j;       // -> M_1 slot

    for (int t = 1; t < L; ++t) {
        float x = xr1; xr1 = xr2; xr2 = xr3; xr3 = xr4;
        xr4 = *lgp;                       // unconditional: pointer is clamped
        if (t < TT - 5) lgp += OO;        // uniform (SGPR) clamp, no branch div

        f32x4 r0,r1,r2,r3,r4,r5,r6,r7,r8,r9,r10,r11,r12,r13,r14,r15;
        asm volatile(
            "ds_read_b128 %0, %16 offset:0\n\t"
            "ds_read_b128 %1, %16 offset:16\n\t"
            "ds_read_b128 %2, %16 offset:32\n\t"
            "ds_read_b128 %3, %16 offset:48\n\t"
            "ds_read_b128 %4, %16 offset:64\n\t"
            "ds_read_b128 %5, %16 offset:80\n\t"
            "ds_read_b128 %6, %16 offset:96\n\t"
            "ds_read_b128 %7, %16 offset:112\n\t"
            "ds_read_b128 %8, %16 offset:128\n\t"
            "ds_read_b128 %9, %16 offset:144\n\t"
            "ds_read_b128 %10, %16 offset:160\n\t"
            "ds_read_b128 %11, %16 offset:176\n\t"
            "ds_read_b128 %12, %16 offset:192\n\t"
            "ds_read_b128 %13, %16 offset:208\n\t"
            "ds_read_b128 %14, %16 offset:224\n\t"
            "ds_read_b128 %15, %16 offset:240\n\t"
            "s_waitcnt lgkmcnt(0)"
            : "=&v"(r0), "=&v"(r1), "=&v"(r2), "=&v"(r3),
              "=&v"(r4), "=&v"(r5), "=&v"(r6), "=&v"(r7),
              "=&v"(r8), "=&v"(r9), "=&v"(r10), "=&v"(r11),
              "=&v"(r12), "=&v"(r13), "=&v"(r14), "=&v"(r15)
            : "v"(stbase));
        __builtin_amdgcn_sched_barrier(0);   // rule-18: pin VALU after wait

        // candidates + max tree, 4 independent partials (max3-friendly)
        float m0, m1, m2, m3;
        #define QUAD(q, rr, acc, first)                                   \
        {                                                                 \
            float c0 = rr[0] + Tc[4*(q)+0];                               \
            float c1 = rr[1] + Tc[4*(q)+1];                               \
            float c2 = rr[2] + Tc[4*(q)+2];                               \
            float c3 = rr[3] + Tc[4*(q)+3];                               \
            float mq = fmaxf(fmaxf(fmaxf(c0, c1), c2), c3);               \
            acc = first ? mq : fmaxf(acc, mq);                            \
        }
        QUAD(0,  r0,  m0, 1) QUAD(1,  r1,  m1, 1)
        QUAD(2,  r2,  m2, 1) QUAD(3,  r3,  m3, 1)
        QUAD(4,  r4,  m0, 0) QUAD(5,  r5,  m1, 0)
        QUAD(6,  r6,  m2, 0) QUAD(7,  r7,  m3, 0)
        QUAD(8,  r8,  m0, 0) QUAD(9,  r9,  m1, 0)
        QUAD(10, r10, m2, 0) QUAD(11, r11, m3, 0)
        QUAD(12, r12, m0, 0) QUAD(13, r13, m1, 0)
        QUAD(14, r14, m2, 0) QUAD(15, r15, m3, 0)
        #undef QUAD
        float m = fmaxf(fmaxf(m0, m1), fmaxf(m2, m3));

        *mwp = m; mwp += OO;            // stream pre-emission max (off-path)
        s = x + m;
        asm volatile("ds_write_b32 %0, %1" :: "v"(wrAddr), "v"(s));
    }

    // ---- final argmax over lanes (first-max, exact) ----
    float mm = s;
    #pragma unroll
    for (int d = 1; d < 64; d <<= 1)
        mm = fmaxf(mm, __shfl_xor(mm, d));
    unsigned long long bal = __ballot(s == mm);
    int gcur = (int)__builtin_ctzll(bal);

    // ---- fused exact backtrack: first i with d_i == M_t[gcur] ----
    int t = L - 1;
    if (j == 0) tagl[t] = (unsigned char)gcur;

    float Mt = Mw[t * OO + j];                          // M_t row (per-lane)
    float Xp = (t >= 1) ? lg[(t - 1) * OO + j] : 0.f;   // x_{t-1} row
    float Mp = (t >= 1) ? Mw[(t - 1) * OO + j] : 0.f;   // M_{t-1} row
    float Xq = (t >= 2) ? lg[(t - 2) * OO + j] : 0.f;   // prefetch t-2
    float Mq = (t >= 2) ? Mw[(t - 2) * OO + j] : 0.f;

    while (t >= 1) {
        float target = __uint_as_float(
            (unsigned)__builtin_amdgcn_readlane(__float_as_uint(Mt), gcur));
        float d = (Xp + Mp) + Tt_lds[gcur * OO + j];    // bit-exact recompute
        unsigned long long bl = __ballot(d == target);
        gcur = (int)__builtin_ctzll(bl);                // first-max semantics
        if (j == 0) tagl[t - 1] = (unsigned char)gcur;
        Mt = Mp; Xp = Xq; Mp = Mq;
        if (t >= 3) {
            Xq = lg[(t - 3) * OO + j];
            Mq = Mw[(t - 3) * OO + j];
        }
        --t;
    }
    asm volatile("" ::: "memory");      // lane0 tagl writes before wave reads

    float* ot = out_tags + (size_t)b * TT;
    for (int p = j; p < TT; p += 64)
        ot[p] = (p < L) ? (float)tagl[p] : 0.f;
}

// =====================================================================
// Kernel 3: confidences for decoded path only. One wave per (b,p).
// s_p = x_p + M_p (bit-exact reconstruction);
// conf = 1 / sum_i exp(v_i - max v),  v_i = s_p[i] + T[i][tag_{p+1}]
// (v_i = s_p[i] for p == L-1). Exact f32.
// =====================================================================
__global__ __launch_bounds__(256) void crf_conf(
    const float* __restrict__ logits,   // [B][T][O]
    const float* __restrict__ Mst,      // ws: [B][T][O]
    const float* __restrict__ Tt,       // ws: [O][O] transposed
    const float* __restrict__ out_tags, // [B][T]
    const int*   __restrict__ seqlens,  // [B]
    float* __restrict__ out_scores)     // [B][T]
{
    const int b = blockIdx.x >> 7;
    const int p = ((blockIdx.x & 127) << 2) + (threadIdx.x >> 6);
    const int i = threadIdx.x & 63;
    const int L = seqlens[b];

    if (p >= L) {
        if (i == 0) out_scores[(size_t)b * TT + p] = 0.f;
        return;
    }

    const size_t row = ((size_t)b * TT + p) * OO;
    float v = logits[row + i] + Mst[row + i];
    if (p < L - 1) {
        int g = (int)out_tags[(size_t)b * TT + p + 1];
        v += Tt[g * OO + i];
    }

    float m = v;
    #pragma unroll
    for (int d = 1; d < 64; d <<= 1)
        m = fmaxf(m, __shfl_xor(m, d));
    float e = __expf(v - m);
    #pragma unroll
    for (int d = 1; d < 64; d <<= 1)
        e += __shfl_xor(e, d);

    if (i == 0)
        out_scores[(size_t)b * TT + p] = 1.0f / e;
}

// =====================================================================
// Fallback (proven round-1 kernel): used only if ws too small
// =====================================================================
__global__ __launch_bounds__(256) void crf_decode_fallback(
    const float* __restrict__ logits,
    const float* __restrict__ trans,
    const int*   __restrict__ seqlens,
    float* __restrict__ out)
{
    const int b   = blockIdx.x;
    const int tid = threadIdx.x;
    const int j   = tid >> 2;
    const int c   = tid & 3;

    __shared__ unsigned char bpl[TT][OO];
    __shared__ unsigned char scl[TT][OO];
    __shared__ float st2[2][OO];

    const int L = seqlens[b];
    const float* lg = logits + (size_t)b * TT * OO;

    float trc[16];
    #pragma unroll
    for (int i2 = 0; i2 < 16; ++i2)
        trc[i2] = trans[(c * 16 + i2) * OO + j];

    if (tid < OO) st2[0][tid] = lg[tid];
    __syncthreads();

    int cur = 0;
    for (int t = 1; t < L; ++t) {
        float x = lg[t * OO + j];
        float v[16];
        float m = -1e30f;
        int   idx = 0;
        #pragma unroll
        for (int i2 = 0; i2 < 16; ++i2) {
            float val = st2[cur][c * 16 + i2] + trc[i2];
            v[i2] = val;
            if (val > m) { m = val; idx = c * 16 + i2; }
        }
        #pragma unroll
        for (int d = 1; d <= 2; d <<= 1) {
            float mo = __shfl_xor(m, d);
            int   io = __shfl_xor(idx, d);
            if (mo > m || (mo == m && io < idx)) { m = mo; idx = io; }
        }
        float sden = 0.f;
        #pragma unroll
        for (int i2 = 0; i2 < 16; ++i2)
            sden += __expf(v[i2] - m);
        #pragma unroll
        for (int d = 1; d <= 2; d <<= 1)
            sden += __shfl_xor(sden, d);

        if (c == 0) {
            st2[cur ^ 1][j] = x + m;
            bpl[t][j] = (unsigned char)idx;
            float conf = fminf(1.0f / sden, 1.0f);
            scl[t][j] = (unsigned char)(conf * 255.0f + 0.5f);
        }
        cur ^= 1;
        __syncthreads();
    }

    if (tid == 0) {
        float m = -1e30f; int idx = 0;
        for (int jj = 0; jj < OO; ++jj) {
            float vv = st2[cur][jj];
            if (vv > m) { m = vv; idx = jj; }
        }
        float sden = 0.f;
        for (int jj = 0; jj < OO; ++jj)
            sden += __expf(st2[cur][jj] - m);

        float* out_tags   = out + (size_t)b * TT;
        float* out_scores = out + (size_t)BB * TT + (size_t)b * TT;
        out_tags[L - 1]   = (float)idx;
        out_scores[L - 1] = 1.0f / sden;

        int tag = idx;
        for (int t = L - 1; t >= 1; --t) {
            int ntag  = bpl[t][tag];
            float sc  = (float)scl[t][tag] * (1.0f / 255.0f);
            out_tags[t - 1]   = (float)ntag;
            out_scores[t - 1] = sc;
            tag = ntag;
        }
    }

    float* out_tags   = out + (size_t)b * TT;
    float* out_scores = out + (size_t)BB * TT + (size_t)b * TT;
    for (int p = L + tid; p < TT; p += 256) {
        out_tags[p]   = 0.f;
        out_scores[p] = 0.f;
    }
}

extern "C" void kernel_launch(void* const* d_in, const int* in_sizes, int n_in,
                              void* d_out, int out_size, void* d_ws, size_t ws_size,
                              hipStream_t stream) {
    const float* logits = (const float*)d_in[0];
    const float* trans  = (const float*)d_in[1];
    const int*   lens   = (const int*)d_in[2];
    float* out = (float*)d_out;

    const size_t m_bytes  = (size_t)BB * TT * OO * sizeof(float); // 64 MB
    const size_t tt_bytes = (size_t)OO * OO * sizeof(float);      // 16 KB
    if (ws_size >= m_bytes + tt_bytes) {
        float* Mst = (float*)d_ws;
        float* Tt  = (float*)((char*)d_ws + m_bytes);
        float* out_tags   = out;
        float* out_scores = out + (size_t)BB * TT;

        crf_transpose<<<1, 256, 0, stream>>>(trans, Tt);
        crf_scan<<<BB, 64, 0, stream>>>(logits, trans, lens, out_tags, Mst);
        crf_conf<<<BB * 128, 256, 0, stream>>>(logits, Mst, Tt, out_tags, lens,
                                               out_scores);
    } else {
        crf_decode_fallback<<<BB, 256, 0, stream>>>(logits, trans, lens, out);
    }
}